// Round 2
// baseline (696.348 us; speedup 1.0000x reference)
//
#include <hip/hip_runtime.h>
#include <math.h>

#define CCH 32              // channels per row
#define QPR 8               // f4 quads per row (32 ch / 4)
#define CAP 256             // sids owned per block
#define PCH 33              // padded LDS table row stride (uints)
#define RPT 8               // consecutive rows per thread (≈ mean run length)
#define CHUNK (32 * RPT)    // rows per block-iteration (32 row-slots x RPT)
#define ENC_NEGINF 0x007FFFFFu

typedef float f4 __attribute__((ext_vector_type(4)));

// Monotonic bijection float -> uint: a < b  <=>  encf(a) < encf(b) (unsigned).
__device__ __forceinline__ unsigned encf(float x) {
    unsigned b = __float_as_uint(x);
    return (b & 0x80000000u) ? ~b : (b | 0x80000000u);
}
// Decode; untouched entries (empty sid) -> +0.0f bits (reference isinf->0 rule).
__device__ __forceinline__ unsigned decbits(unsigned u) {
    if (u == ENC_NEGINF) return 0u;
    return (u & 0x80000000u) ? (u ^ 0x80000000u) : ~u;
}

__device__ __forceinline__ f4 f4max(f4 a, f4 b) {
    f4 r;
    r.x = fmaxf(a.x, b.x);
    r.y = fmaxf(a.y, b.y);
    r.z = fmaxf(a.z, b.z);
    r.w = fmaxf(a.w, b.w);
    return r;
}

// K0: startc[j] = lower_bound(ids, j*CAP) for j in [0, NB].
__global__ void bounds_kernel(const int* __restrict__ ids,
                              int* __restrict__ startc,
                              int N, int NB) {
    int j = blockIdx.x * blockDim.x + threadIdx.x;
    if (j > NB) return;
    int target = j * CAP;
    int lo = 0, hi = N;
    while (lo < hi) {
        int mid = (lo + hi) >> 1;
        if (ids[mid] < target) lo = mid + 1;
        else hi = mid;
    }
    startc[j] = lo;
}

// K1: block b owns sids [b*CAP,(b+1)*CAP) and rows [startc[b], startc[b+1]).
// Each thread takes RPT *consecutive* rows per chunk and merges same-sid rows
// in registers (sorted ids => ~1.9 runs per 8 rows); LDS atomicMax only at
// run boundaries. Loads stay full-cacheline coalesced (each wave-load = 8
// distinct 128B lines). This cuts LDS atomic traffic ~4x and same-address
// serialization ~8x vs the round-1 stride-32 mapping.
__global__ __launch_bounds__(256) void pool_kernel(
    const f4* __restrict__ feat, const int* __restrict__ ids,
    const int* __restrict__ startc, unsigned* __restrict__ out,
    int M) {
    __shared__ unsigned tab[CAP * PCH];
    const int b    = blockIdx.x;
    const int sid0 = b * CAP;
    const int rs   = startc[b];
    const int re   = startc[b + 1];
    const int tid  = threadIdx.x;
    const int q    = tid & (QPR - 1);   // quad (4 channels) within row
    const int rofs = tid >> 3;          // row slot 0..31
    const int c0   = q * 4;

    for (int e = tid; e < CAP * PCH; e += 256) tab[e] = ENC_NEGINF;
    __syncthreads();

    int cbase = rs;
    for (; cbase + CHUNK <= re; cbase += CHUNK) {
        const int r0 = cbase + rofs * RPT;
        f4  v[RPT];
        int s[RPT];
        // Issue all 16 independent loads before any use.
        #pragma unroll
        for (int k = 0; k < RPT; ++k) v[k] = feat[(size_t)(r0 + k) * QPR + q];
        #pragma unroll
        for (int k = 0; k < RPT; ++k) s[k] = ids[r0 + k];

        f4  acc = v[0];
        int cs  = s[0];
        #pragma unroll
        for (int k = 1; k < RPT; ++k) {
            if (s[k] == cs) {
                acc = f4max(acc, v[k]);
            } else {
                unsigned* t = tab + (cs - sid0) * PCH + c0;
                atomicMax(t + 0, encf(acc.x));
                atomicMax(t + 1, encf(acc.y));
                atomicMax(t + 2, encf(acc.z));
                atomicMax(t + 3, encf(acc.w));
                acc = v[k];
                cs  = s[k];
            }
        }
        {
            unsigned* t = tab + (cs - sid0) * PCH + c0;
            atomicMax(t + 0, encf(acc.x));
            atomicMax(t + 1, encf(acc.y));
            atomicMax(t + 2, encf(acc.z));
            atomicMax(t + 3, encf(acc.w));
        }
    }

    // Tail chunk (< CHUNK rows), per-row masked.
    if (cbase < re) {
        const int r0 = cbase + rofs * RPT;
        f4  acc;
        int cs = -1;
        #pragma unroll
        for (int k = 0; k < RPT; ++k) {
            int r = r0 + k;
            if (r < re) {
                f4  vv = feat[(size_t)r * QPR + q];
                int ss = ids[r];
                if (ss == cs) {
                    acc = f4max(acc, vv);
                } else {
                    if (cs >= 0) {
                        unsigned* t = tab + (cs - sid0) * PCH + c0;
                        atomicMax(t + 0, encf(acc.x));
                        atomicMax(t + 1, encf(acc.y));
                        atomicMax(t + 2, encf(acc.z));
                        atomicMax(t + 3, encf(acc.w));
                    }
                    acc = vv;
                    cs  = ss;
                }
            }
        }
        if (cs >= 0) {
            unsigned* t = tab + (cs - sid0) * PCH + c0;
            atomicMax(t + 0, encf(acc.x));
            atomicMax(t + 1, encf(acc.y));
            atomicMax(t + 2, encf(acc.z));
            atomicMax(t + 3, encf(acc.w));
        }
    }
    __syncthreads();

    // Flush: each of this block's sids written exactly once (zeros for empty).
    int nsid = M - sid0; if (nsid > CAP) nsid = CAP;
    unsigned* ob = out + (size_t)sid0 * CCH;
    for (int e = tid; e < nsid * CCH; e += 256) {
        unsigned u = tab[(e >> 5) * PCH + (e & 31)];
        ob[e] = decbits(u);
    }
}

extern "C" void kernel_launch(void* const* d_in, const int* in_sizes, int n_in,
                              void* d_out, int out_size, void* d_ws, size_t ws_size,
                              hipStream_t stream) {
    const f4*  feat = (const f4*)d_in[0];
    const int* ids  = (const int*)d_in[1];

    const int N  = in_sizes[0] / CCH;        // 4,000,000
    const int M  = out_size / CCH;           // 500,000
    const int NB = (M + CAP - 1) / CAP;      // 1954

    int* startc = (int*)d_ws;                // (NB+1) ints

    int gridA = (NB + 1 + 255) / 256;
    bounds_kernel<<<gridA, 256, 0, stream>>>(ids, startc, N, NB);
    pool_kernel<<<NB, 256, 0, stream>>>(feat, ids, startc,
                                        (unsigned*)d_out, M);
}